// Round 1
// baseline (584.732 us; speedup 1.0000x reference)
//
#include <hip/hip_runtime.h>
#include <hip/hip_bf16.h>

#define NN   50000
#define E0   800000
#define ET   850000
#define FIN  166
#define KP1  192
#define HID  64
#define NH   8
#define F1   512
#define SCHUNK 49

typedef __attribute__((ext_vector_type(8))) short short8;
typedef __attribute__((ext_vector_type(4))) float f32x4;

__device__ __forceinline__ float bf2f(unsigned short u){
  unsigned int x = ((unsigned int)u) << 16;
  return __builtin_bit_cast(float, x);
}
__device__ __forceinline__ unsigned short f2bf(float f){
  unsigned int x = __builtin_bit_cast(unsigned int, f);
  x += 0x7FFFu + ((x >> 16) & 1u);
  return (unsigned short)(x >> 16);
}

// ---- pad + convert x (f32 [NN,166]) -> xpad (bf16 [NN,192]) ----
__global__ __launch_bounds__(256) void k_pad_x(const float* __restrict__ x,
                                               unsigned short* __restrict__ xpad){
  const long long total = (long long)NN * KP1;
  for (long long i = (long long)blockIdx.x*256 + threadIdx.x; i < total;
       i += (long long)gridDim.x*256){
    int n = (int)(i / KP1), k = (int)(i % KP1);
    float v = (k < FIN) ? x[(size_t)n*FIN + k] : 0.f;
    xpad[i] = f2bf(v);
  }
}

// ---- degree histogram over dst (incl self loops) ----
__global__ __launch_bounds__(256) void k_hist(const int* __restrict__ ei,
                                              int* __restrict__ deg){
  for (int e = blockIdx.x*256 + threadIdx.x; e < ET; e += gridDim.x*256){
    int dst = (e < E0) ? ei[E0 + e] : (e - E0);
    atomicAdd(&deg[dst], 1);
  }
}

// ---- exclusive scan of deg -> offs[NN+1], single block ----
__global__ __launch_bounds__(1024) void k_scan(const int* __restrict__ deg,
                                               int* __restrict__ offs){
  __shared__ int sums[1024];
  int t = threadIdx.x;
  int start = t * SCHUNK, end = min(start + SCHUNK, NN);
  int loc = 0;
  for (int i = start; i < end; i++) loc += deg[i];
  sums[t] = loc; __syncthreads();
  for (int off = 1; off < 1024; off <<= 1){
    int v = (t >= off) ? sums[t - off] : 0;
    __syncthreads();
    sums[t] += v;
    __syncthreads();
  }
  int run = sums[t] - loc; // exclusive prefix of this chunk
  for (int i = start; i < end; i++){ offs[i] = run; run += deg[i]; }
  if (t == 1023) offs[NN] = sums[1023];
}

// ---- scatter edges into CSR-by-dst (store src only) ----
__global__ __launch_bounds__(256) void k_scatter(const int* __restrict__ ei,
                                                 const int* __restrict__ offs,
                                                 int* __restrict__ cur,
                                                 int* __restrict__ esrc){
  for (int e = blockIdx.x*256 + threadIdx.x; e < ET; e += gridDim.x*256){
    int src, dst;
    if (e < E0){ src = ei[e]; dst = ei[E0 + e]; }
    else       { src = e - E0; dst = src; }
    int pos = offs[dst] + atomicAdd(&cur[dst], 1);
    esrc[pos] = src;
  }
}

// ---- bf16 MFMA GEMM: A(bf16 [M,lda]) @ B(f32 [kvalid,ldb]) -> C [M,ldb] ----
// 64x64 tile, 4 waves (2x2), each wave 32x32 via 2x2 16x16x32 fragments.
template<int KSTEPS, bool OUT_BF16>
__global__ __launch_bounds__(256) void k_gemm(const unsigned short* __restrict__ A,
                                              int lda, int M,
                                              const float* __restrict__ B,
                                              int ldb, int kvalid,
                                              void* __restrict__ C){
  __shared__ unsigned short As[64][40];  // row stride 80B: 2-way-bank-conflict-free-ish
  __shared__ unsigned short Bt[64][40];  // B transposed: [col][k]
  const int m0 = blockIdx.x * 64;
  const int n0 = blockIdx.y * 64;
  const int t  = threadIdx.x;
  const int wid = t >> 6, l = t & 63;
  const int wr = wid >> 1, wc = wid & 1;
  const int lr = l & 15, ksl = (l >> 4) * 8;

  f32x4 acc[2][2];
  #pragma unroll
  for (int m = 0; m < 2; m++)
    #pragma unroll
    for (int n = 0; n < 2; n++)
      #pragma unroll
      for (int j = 0; j < 4; j++) acc[m][n][j] = 0.f;

  const int arow = t >> 2, akc = (t & 3) * 8;
  const int bn   = t >> 2, bks = (t & 3) * 8;

  for (int s = 0; s < KSTEPS; s++){
    const int kk = s * 32;
    // stage A tile [64 x 32]
    short8 av;
    #pragma unroll
    for (int j = 0; j < 8; j++) av[j] = 0;
    int gr = m0 + arow;
    if (gr < M) av = *(const short8*)(A + (size_t)gr*lda + kk + akc);
    *(short8*)&As[arow][akc] = av;
    // stage B tile transposed [64 x 32], f32 -> bf16
    int gc = n0 + bn;
    short8 bv;
    #pragma unroll
    for (int j = 0; j < 8; j++){
      int kg = kk + bks + j;
      float f = (kg < kvalid) ? B[(size_t)kg*ldb + gc] : 0.f;
      bv[j] = (short)f2bf(f);
    }
    *(short8*)&Bt[bn][bks] = bv;
    __syncthreads();

    short8 af[2], bf_[2];
    #pragma unroll
    for (int m = 0; m < 2; m++) af[m]  = *(const short8*)&As[wr*32 + m*16 + lr][ksl];
    #pragma unroll
    for (int n = 0; n < 2; n++) bf_[n] = *(const short8*)&Bt[wc*32 + n*16 + lr][ksl];
    #pragma unroll
    for (int m = 0; m < 2; m++)
      #pragma unroll
      for (int n = 0; n < 2; n++)
        acc[m][n] = __builtin_amdgcn_mfma_f32_16x16x32_bf16(af[m], bf_[n], acc[m][n], 0, 0, 0);
    __syncthreads();
  }

  #pragma unroll
  for (int m = 0; m < 2; m++)
    #pragma unroll
    for (int n = 0; n < 2; n++)
      #pragma unroll
      for (int j = 0; j < 4; j++){
        int gr = m0 + wr*32 + m*16 + (l >> 4)*4 + j;
        int gc = n0 + wc*32 + n*16 + lr;
        if (gr < M){
          if (OUT_BF16) ((unsigned short*)C)[(size_t)gr*ldb + gc] = f2bf(acc[m][n][j]);
          else          ((float*)C)[(size_t)gr*ldb + gc]          = acc[m][n][j];
        }
      }
}

// ---- per-node attention logits, layer 1 (wave per node) ----
__global__ __launch_bounds__(256) void k_al1(const unsigned short* __restrict__ xp1,
                                             const float* __restrict__ a_s,
                                             const float* __restrict__ a_d,
                                             float* __restrict__ als,
                                             float* __restrict__ ald){
  int w = (blockIdx.x*256 + threadIdx.x) >> 6;
  int l = threadIdx.x & 63;
  if (w >= NN) return;
  short8 v = *(const short8*)(xp1 + (size_t)w*F1 + l*8);
  int h = l >> 3;
  int cb = h*64 + (l & 7)*8;
  float ps = 0.f, pd = 0.f;
  #pragma unroll
  for (int j = 0; j < 8; j++){
    float x = bf2f((unsigned short)v[j]);
    ps = fmaf(x, a_s[cb + j], ps);
    pd = fmaf(x, a_d[cb + j], pd);
  }
  #pragma unroll
  for (int o = 1; o < 8; o <<= 1){
    ps += __shfl_xor(ps, o, 64);
    pd += __shfl_xor(pd, o, 64);
  }
  if ((l & 7) == 0){ als[w*NH + h] = ps; ald[w*NH + h] = pd; }
}

// ---- layer-1 aggregation: wave per dst node; lane owns 8 of 512 feats ----
__global__ __launch_bounds__(256) void k_agg1(const int* __restrict__ offs,
                                              const int* __restrict__ esrc,
                                              const unsigned short* __restrict__ xp1,
                                              const float* __restrict__ als,
                                              const float* __restrict__ ald,
                                              const float* __restrict__ b1,
                                              unsigned short* __restrict__ h1){
  int w = (blockIdx.x*256 + threadIdx.x) >> 6;
  int l = threadIdx.x & 63;
  if (w >= NN) return;
  int h = l >> 3;
  int f0 = l * 8;
  float ad = ald[w*NH + h];
  int s0 = offs[w], s1 = offs[w+1];
  float mx = -1e30f;
  for (int i = s0; i < s1; i++){
    int s = esrc[i];
    float e = als[s*NH + h] + ad;
    e = e > 0.f ? e : 0.2f*e;
    mx = fmaxf(mx, e);
  }
  float acc[8];
  #pragma unroll
  for (int j = 0; j < 8; j++) acc[j] = 0.f;
  float den = 0.f;
  for (int i = s0; i < s1; i++){
    int s = esrc[i];
    float e = als[s*NH + h] + ad;
    e = e > 0.f ? e : 0.2f*e;
    float wt = __expf(e - mx);
    den += wt;
    short8 v = *(const short8*)(xp1 + (size_t)s*F1 + f0);
    #pragma unroll
    for (int j = 0; j < 8; j++) acc[j] = fmaf(wt, bf2f((unsigned short)v[j]), acc[j]);
  }
  float inv = 1.f / den;
  #pragma unroll
  for (int j = 0; j < 8; j++){
    float o = acc[j]*inv + b1[f0 + j];
    o = o > 0.f ? o : expm1f(o);          // ELU
    h1[(size_t)w*F1 + f0 + j] = f2bf(o);
  }
}

// ---- per-node attention logits, layer 2 (wave per node, 1 head) ----
__global__ __launch_bounds__(256) void k_al2(const float* __restrict__ xp2,
                                             const float* __restrict__ a_s,
                                             const float* __restrict__ a_d,
                                             float* __restrict__ als,
                                             float* __restrict__ ald){
  int w = (blockIdx.x*256 + threadIdx.x) >> 6;
  int l = threadIdx.x & 63;
  if (w >= NN) return;
  float x = xp2[(size_t)w*HID + l];
  float ps = x * a_s[l];
  float pd = x * a_d[l];
  #pragma unroll
  for (int o = 1; o < 64; o <<= 1){
    ps += __shfl_xor(ps, o, 64);
    pd += __shfl_xor(pd, o, 64);
  }
  if (l == 0){ als[w] = ps; ald[w] = pd; }
}

// ---- layer-2 aggregation + fused classifier MLP (wave per node) ----
__global__ __launch_bounds__(256) void k_agg2(const int* __restrict__ offs,
                                              const int* __restrict__ esrc,
                                              const float* __restrict__ xp2,
                                              const float* __restrict__ als,
                                              const float* __restrict__ ald,
                                              const float* __restrict__ b2,
                                              const float* __restrict__ Wc1,
                                              const float* __restrict__ bc1,
                                              const float* __restrict__ Wc2,
                                              const float* __restrict__ bc2,
                                              float* __restrict__ out){
  int w = (blockIdx.x*256 + threadIdx.x) >> 6;
  int l = threadIdx.x & 63;
  if (w >= NN) return;
  float ad = ald[w];
  int s0 = offs[w], s1 = offs[w+1];
  float mx = -1e30f;
  for (int i = s0; i < s1; i++){
    float e = als[esrc[i]] + ad;
    e = e > 0.f ? e : 0.2f*e;
    mx = fmaxf(mx, e);
  }
  float acc = 0.f, den = 0.f;
  for (int i = s0; i < s1; i++){
    int s = esrc[i];
    float e = als[s] + ad;
    e = e > 0.f ? e : 0.2f*e;
    float wt = __expf(e - mx);
    den += wt;
    acc = fmaf(wt, xp2[(size_t)s*HID + l], acc);
  }
  float h2 = acc / den + b2[l];
  // r = relu(h2 @ Wc1 + bc1)
  float r = 0.f;
  #pragma unroll
  for (int k = 0; k < 64; k++){
    float hk = __shfl(h2, k, 64);
    r = fmaf(hk, Wc1[k*HID + l], r);
  }
  r += bc1[l];
  r = fmaxf(r, 0.f);
  // out = r @ Wc2 + bc2  (2 classes, full-wave reduce)
  float p0 = r * Wc2[l*2 + 0];
  float p1 = r * Wc2[l*2 + 1];
  #pragma unroll
  for (int o = 1; o < 64; o <<= 1){
    p0 += __shfl_xor(p0, o, 64);
    p1 += __shfl_xor(p1, o, 64);
  }
  if (l == 0){
    out[(size_t)w*2 + 0] = p0 + bc2[0];
    out[(size_t)w*2 + 1] = p1 + bc2[1];
  }
}

extern "C" void kernel_launch(void* const* d_in, const int* in_sizes, int n_in,
                              void* d_out, int out_size, void* d_ws, size_t ws_size,
                              hipStream_t stream){
  const float* x   = (const float*)d_in[0];
  const int*   ei  = (const int*)  d_in[1];
  const float* W1  = (const float*)d_in[2];
  const float* as1 = (const float*)d_in[3];
  const float* ad1 = (const float*)d_in[4];
  const float* b1  = (const float*)d_in[5];
  const float* W2  = (const float*)d_in[6];
  const float* as2 = (const float*)d_in[7];
  const float* ad2 = (const float*)d_in[8];
  const float* b2  = (const float*)d_in[9];
  const float* Wc1 = (const float*)d_in[10];
  const float* bc1 = (const float*)d_in[11];
  const float* Wc2 = (const float*)d_in[12];
  const float* bc2 = (const float*)d_in[13];
  float* out = (float*)d_out;

  char* p = (char*)d_ws; size_t off = 0;
  auto alloc = [&](size_t b){ void* r = p + off; off = (off + b + 255) & ~(size_t)255; return r; };
  unsigned short* xpad = (unsigned short*)alloc((size_t)NN*KP1*2);
  unsigned short* xp1  = (unsigned short*)alloc((size_t)NN*F1*2);
  unsigned short* h1   = (unsigned short*)alloc((size_t)NN*F1*2);
  float* xp2  = (float*)alloc((size_t)NN*HID*4);
  float* als1 = (float*)alloc((size_t)NN*NH*4);
  float* ald1 = (float*)alloc((size_t)NN*NH*4);
  float* als2 = (float*)alloc((size_t)NN*4);
  float* ald2 = (float*)alloc((size_t)NN*4);
  int* deg  = (int*)alloc((size_t)NN*4);
  int* cur  = (int*)alloc((size_t)NN*4);
  int* offs = (int*)alloc((size_t)(NN+1)*4);
  int* esrc = (int*)alloc((size_t)ET*4);

  hipMemsetAsync(deg, 0, (size_t)NN*4, stream);
  hipMemsetAsync(cur, 0, (size_t)NN*4, stream);

  k_pad_x<<<4096, 256, 0, stream>>>(x, xpad);
  k_hist<<<(ET + 255)/256, 256, 0, stream>>>(ei, deg);
  k_scan<<<1, 1024, 0, stream>>>(deg, offs);
  k_scatter<<<(ET + 255)/256, 256, 0, stream>>>(ei, offs, cur, esrc);

  k_gemm<6, true><<<dim3(782, 8), 256, 0, stream>>>(xpad, KP1, NN, W1, F1, FIN, (void*)xp1);
  k_al1<<<12500, 256, 0, stream>>>(xp1, as1, ad1, als1, ald1);
  k_agg1<<<12500, 256, 0, stream>>>(offs, esrc, xp1, als1, ald1, b1, h1);

  k_gemm<16, false><<<dim3(782, 1), 256, 0, stream>>>(h1, F1, NN, W2, HID, F1, (void*)xp2);
  k_al2<<<12500, 256, 0, stream>>>(xp2, as2, ad2, als2, ald2);
  k_agg2<<<12500, 256, 0, stream>>>(offs, esrc, xp2, als2, ald2, b2, Wc1, bc1, Wc2, bc2, out);
}

// Round 2
// 404.443 us; speedup vs baseline: 1.4458x; 1.4458x over previous
//
#include <hip/hip_runtime.h>

#define NN   50000
#define E0   800000
#define ET   850000
#define FIN  166
#define KP1  192
#define HID  64
#define NH   8
#define F1   512
#define SCHUNK 52
#define DEGPAD (1024*SCHUNK)

typedef __attribute__((ext_vector_type(8))) short short8;
typedef __attribute__((ext_vector_type(4))) float f32x4;
typedef __attribute__((ext_vector_type(4))) int int4v;

__device__ __forceinline__ float bf2f(unsigned short u){
  unsigned int x = ((unsigned int)u) << 16;
  return __builtin_bit_cast(float, x);
}
__device__ __forceinline__ unsigned short f2bf(float f){
  unsigned int x = __builtin_bit_cast(unsigned int, f);
  x += 0x7FFFu + ((x >> 16) & 1u);
  return (unsigned short)(x >> 16);
}

// ---- pad + convert x (f32 [NN,166]) -> xpad (bf16 [NN,192]) ----
__global__ __launch_bounds__(256) void k_pad_x(const float* __restrict__ x,
                                               unsigned short* __restrict__ xpad){
  const long long total = (long long)NN * KP1;
  for (long long i = (long long)blockIdx.x*256 + threadIdx.x; i < total;
       i += (long long)gridDim.x*256){
    int n = (int)(i / KP1), k = (int)(i % KP1);
    float v = (k < FIN) ? x[(size_t)n*FIN + k] : 0.f;
    xpad[i] = f2bf(v);
  }
}

// ---- transpose+convert weights: W1[166,512]->W1t[512][192] bf16, W2[512,64]->W2t[64][512] ----
__global__ __launch_bounds__(256) void k_prep(const float* __restrict__ W1,
                                              const float* __restrict__ W2,
                                              unsigned short* __restrict__ W1t,
                                              unsigned short* __restrict__ W2t){
  const int tot1 = 512*KP1, tot2 = HID*F1;
  int i = blockIdx.x*256 + threadIdx.x;
  if (i < tot1){
    int col = i / KP1, k = i % KP1;
    float v = (k < FIN) ? W1[(size_t)k*512 + col] : 0.f;
    W1t[i] = f2bf(v);
  } else if (i < tot1 + tot2){
    int j = i - tot1;
    int col = j / F1, k = j % F1;
    W2t[j] = f2bf(W2[(size_t)k*HID + col]);
  }
}

// ---- degree histogram over dst (incl self loops) ----
__global__ __launch_bounds__(256) void k_hist(const int* __restrict__ ei,
                                              int* __restrict__ deg){
  for (int e = blockIdx.x*256 + threadIdx.x; e < ET; e += gridDim.x*256){
    int dst = (e < E0) ? ei[E0 + e] : (e - E0);
    atomicAdd(&deg[dst], 1);
  }
}

// ---- exclusive scan of deg -> offs[NN+1], single block, int4 loads ----
__global__ __launch_bounds__(1024) void k_scan(const int* __restrict__ deg,
                                               int* __restrict__ offs){
  __shared__ int sums[1024];
  int t = threadIdx.x;
  int base = t * SCHUNK;
  int4v v[13];
  int loc = 0;
  #pragma unroll
  for (int c = 0; c < 13; c++){
    v[c] = *(const int4v*)(deg + base + c*4);
    loc += v[c].x + v[c].y + v[c].z + v[c].w;
  }
  sums[t] = loc; __syncthreads();
  for (int off = 1; off < 1024; off <<= 1){
    int s = (t >= off) ? sums[t - off] : 0;
    __syncthreads();
    sums[t] += s;
    __syncthreads();
  }
  int run = sums[t] - loc;
  #pragma unroll
  for (int c = 0; c < 13; c++){
    int i0 = base + c*4;
    if (i0 + 0 < NN) offs[i0 + 0] = run;  run += v[c].x;
    if (i0 + 1 < NN) offs[i0 + 1] = run;  run += v[c].y;
    if (i0 + 2 < NN) offs[i0 + 2] = run;  run += v[c].z;
    if (i0 + 3 < NN) offs[i0 + 3] = run;  run += v[c].w;
  }
  if (t == 1023) offs[NN] = sums[1023];
}

// ---- scatter edges into CSR-by-dst (store src only) ----
__global__ __launch_bounds__(256) void k_scatter(const int* __restrict__ ei,
                                                 const int* __restrict__ offs,
                                                 int* __restrict__ cur,
                                                 int* __restrict__ esrc){
  for (int e = blockIdx.x*256 + threadIdx.x; e < ET; e += gridDim.x*256){
    int src, dst;
    if (e < E0){ src = ei[e]; dst = ei[E0 + e]; }
    else       { src = e - E0; dst = src; }
    int pos = offs[dst] + atomicAdd(&cur[dst], 1);
    esrc[pos] = src;
  }
}

// ---- bf16 MFMA GEMM: A(bf16 [M,lda]) @ Bt(bf16 [Ncols][lda]) -> C [M,ldc] ----
// 64x64 tile, 4 waves (2x2), 2x2 16x16x32 fragments per wave.
// DO_AL: fused attention-logit epilogue: als/ald[row*ALH + head], head=blockIdx.y (ALH>1) or 0.
template<int KSTEPS, bool OUT_BF16, bool DO_AL, int ALH>
__global__ __launch_bounds__(256) void k_gemm(const unsigned short* __restrict__ A,
                                              int lda, int M,
                                              const unsigned short* __restrict__ Bt,
                                              void* __restrict__ C, int ldc,
                                              const float* __restrict__ a_s,
                                              const float* __restrict__ a_d,
                                              float* __restrict__ als,
                                              float* __restrict__ ald){
  __shared__ unsigned short As[64][40];
  __shared__ unsigned short Bs[64][40];
  __shared__ float redS[64][2];
  __shared__ float redD[64][2];
  const int m0 = blockIdx.x * 64;
  const int n0 = blockIdx.y * 64;
  const int t  = threadIdx.x;
  const int wid = t >> 6, l = t & 63;
  const int wr = wid >> 1, wc = wid & 1;
  const int lr = l & 15, ksl = (l >> 4) * 8;

  f32x4 acc[2][2];
  #pragma unroll
  for (int m = 0; m < 2; m++)
    #pragma unroll
    for (int n = 0; n < 2; n++)
      #pragma unroll
      for (int j = 0; j < 4; j++) acc[m][n][j] = 0.f;

  const int arow = t >> 2, akc = (t & 3) * 8;

  for (int s = 0; s < KSTEPS; s++){
    const int kk = s * 32;
    short8 av;
    #pragma unroll
    for (int j = 0; j < 8; j++) av[j] = 0;
    int gr = m0 + arow;
    if (gr < M) av = *(const short8*)(A + (size_t)gr*lda + kk + akc);
    *(short8*)&As[arow][akc] = av;
    short8 bv = *(const short8*)(Bt + (size_t)(n0 + arow)*lda + kk + akc);
    *(short8*)&Bs[arow][akc] = bv;
    __syncthreads();

    short8 af[2], bf_[2];
    #pragma unroll
    for (int m = 0; m < 2; m++) af[m]  = *(const short8*)&As[wr*32 + m*16 + lr][ksl];
    #pragma unroll
    for (int n = 0; n < 2; n++) bf_[n] = *(const short8*)&Bs[wc*32 + n*16 + lr][ksl];
    #pragma unroll
    for (int m = 0; m < 2; m++)
      #pragma unroll
      for (int n = 0; n < 2; n++)
        acc[m][n] = __builtin_amdgcn_mfma_f32_16x16x32_bf16(af[m], bf_[n], acc[m][n], 0, 0, 0);
    __syncthreads();
  }

  #pragma unroll
  for (int m = 0; m < 2; m++)
    #pragma unroll
    for (int n = 0; n < 2; n++)
      #pragma unroll
      for (int j = 0; j < 4; j++){
        int gr = m0 + wr*32 + m*16 + (l >> 4)*4 + j;
        int gc = n0 + wc*32 + n*16 + lr;
        if (gr < M){
          if (OUT_BF16) ((unsigned short*)C)[(size_t)gr*ldc + gc] = f2bf(acc[m][n][j]);
          else          ((float*)C)[(size_t)gr*ldc + gc]          = acc[m][n][j];
        }
      }

  if (DO_AL){
    const float* asp = a_s + (ALH > 1 ? (int)blockIdx.y*64 : 0);
    const float* adp = a_d + (ALH > 1 ? (int)blockIdx.y*64 : 0);
    float c0 = asp[wc*32 + lr],      c1 = asp[wc*32 + 16 + lr];
    float d0 = adp[wc*32 + lr],      d1 = adp[wc*32 + 16 + lr];
    #pragma unroll
    for (int m = 0; m < 2; m++)
      #pragma unroll
      for (int j = 0; j < 4; j++){
        float ps = acc[m][0][j]*c0 + acc[m][1][j]*c1;
        float pd = acc[m][0][j]*d0 + acc[m][1][j]*d1;
        #pragma unroll
        for (int o = 1; o < 16; o <<= 1){
          ps += __shfl_xor(ps, o, 64);
          pd += __shfl_xor(pd, o, 64);
        }
        if (lr == 0){
          int rl = wr*32 + m*16 + (l >> 4)*4 + j;
          redS[rl][wc] = ps;
          redD[rl][wc] = pd;
        }
      }
    __syncthreads();
    if (t < 64){
      int gr = m0 + t;
      if (gr < M){
        float s = redS[t][0] + redS[t][1];
        float d = redD[t][0] + redD[t][1];
        s = fminf(fmaxf(s, -30.f), 30.f);
        d = fminf(fmaxf(d, -30.f), 30.f);
        int head = (ALH > 1) ? blockIdx.y : 0;
        als[(size_t)gr*ALH + head] = s;
        ald[(size_t)gr*ALH + head] = d;
      }
    }
  }
}

// ---- layer-1 aggregation: wave per dst node; no max pass; 2-way unroll ----
__global__ __launch_bounds__(256) void k_agg1(const int* __restrict__ offs,
                                              const int* __restrict__ esrc,
                                              const unsigned short* __restrict__ xp1,
                                              const float* __restrict__ als,
                                              const float* __restrict__ ald,
                                              const float* __restrict__ b1,
                                              unsigned short* __restrict__ h1){
  int w = (blockIdx.x*256 + threadIdx.x) >> 6;
  int l = threadIdx.x & 63;
  if (w >= NN) return;
  int h = l >> 3;
  int f0 = l * 8;
  float ad = ald[w*NH + h];
  int s0 = offs[w], s1 = offs[w+1];
  float accA[8], accB[8];
  #pragma unroll
  for (int j = 0; j < 8; j++){ accA[j] = 0.f; accB[j] = 0.f; }
  float denA = 0.f, denB = 0.f;
  int i = s0;
  for (; i + 2 <= s1; i += 2){
    int sA = esrc[i], sB = esrc[i+1];
    float eA = als[sA*NH + h] + ad;
    float eB = als[sB*NH + h] + ad;
    eA = fmaxf(eA, 0.2f*eA);
    eB = fmaxf(eB, 0.2f*eB);
    float wA = __expf(eA), wB = __expf(eB);
    short8 vA = *(const short8*)(xp1 + (size_t)sA*F1 + f0);
    short8 vB = *(const short8*)(xp1 + (size_t)sB*F1 + f0);
    denA += wA; denB += wB;
    #pragma unroll
    for (int j = 0; j < 8; j++){
      accA[j] = fmaf(wA, bf2f((unsigned short)vA[j]), accA[j]);
      accB[j] = fmaf(wB, bf2f((unsigned short)vB[j]), accB[j]);
    }
  }
  if (i < s1){
    int sA = esrc[i];
    float eA = als[sA*NH + h] + ad;
    eA = fmaxf(eA, 0.2f*eA);
    float wA = __expf(eA);
    short8 vA = *(const short8*)(xp1 + (size_t)sA*F1 + f0);
    denA += wA;
    #pragma unroll
    for (int j = 0; j < 8; j++) accA[j] = fmaf(wA, bf2f((unsigned short)vA[j]), accA[j]);
  }
  float inv = 1.f / (denA + denB);
  #pragma unroll
  for (int j = 0; j < 8; j++){
    float o = (accA[j] + accB[j])*inv + b1[f0 + j];
    o = o > 0.f ? o : expm1f(o);          // ELU
    h1[(size_t)w*F1 + f0 + j] = f2bf(o);
  }
}

// ---- layer-2 aggregation + fused classifier MLP (wave per node); no max pass ----
__global__ __launch_bounds__(256) void k_agg2(const int* __restrict__ offs,
                                              const int* __restrict__ esrc,
                                              const float* __restrict__ xp2,
                                              const float* __restrict__ als,
                                              const float* __restrict__ ald,
                                              const float* __restrict__ b2,
                                              const float* __restrict__ Wc1,
                                              const float* __restrict__ bc1,
                                              const float* __restrict__ Wc2,
                                              const float* __restrict__ bc2,
                                              float* __restrict__ out){
  int w = (blockIdx.x*256 + threadIdx.x) >> 6;
  int l = threadIdx.x & 63;
  if (w >= NN) return;
  float ad = ald[w];
  int s0 = offs[w], s1 = offs[w+1];
  float accA = 0.f, accB = 0.f, denA = 0.f, denB = 0.f;
  int i = s0;
  for (; i + 2 <= s1; i += 2){
    int sA = esrc[i], sB = esrc[i+1];
    float eA = als[sA] + ad;
    float eB = als[sB] + ad;
    eA = fmaxf(eA, 0.2f*eA);
    eB = fmaxf(eB, 0.2f*eB);
    float wA = __expf(eA), wB = __expf(eB);
    float xA = xp2[(size_t)sA*HID + l];
    float xB = xp2[(size_t)sB*HID + l];
    denA += wA; denB += wB;
    accA = fmaf(wA, xA, accA);
    accB = fmaf(wB, xB, accB);
  }
  if (i < s1){
    int sA = esrc[i];
    float eA = als[sA] + ad;
    eA = fmaxf(eA, 0.2f*eA);
    float wA = __expf(eA);
    denA += wA;
    accA = fmaf(wA, xp2[(size_t)sA*HID + l], accA);
  }
  float h2 = (accA + accB) / (denA + denB) + b2[l];
  // r = relu(h2 @ Wc1 + bc1)
  float r = 0.f;
  #pragma unroll
  for (int k = 0; k < 64; k++){
    float hk = __shfl(h2, k, 64);
    r = fmaf(hk, Wc1[k*HID + l], r);
  }
  r += bc1[l];
  r = fmaxf(r, 0.f);
  float p0 = r * Wc2[l*2 + 0];
  float p1 = r * Wc2[l*2 + 1];
  #pragma unroll
  for (int o = 1; o < 64; o <<= 1){
    p0 += __shfl_xor(p0, o, 64);
    p1 += __shfl_xor(p1, o, 64);
  }
  if (l == 0){
    out[(size_t)w*2 + 0] = p0 + bc2[0];
    out[(size_t)w*2 + 1] = p1 + bc2[1];
  }
}

extern "C" void kernel_launch(void* const* d_in, const int* in_sizes, int n_in,
                              void* d_out, int out_size, void* d_ws, size_t ws_size,
                              hipStream_t stream){
  const float* x   = (const float*)d_in[0];
  const int*   ei  = (const int*)  d_in[1];
  const float* W1  = (const float*)d_in[2];
  const float* as1 = (const float*)d_in[3];
  const float* ad1 = (const float*)d_in[4];
  const float* b1  = (const float*)d_in[5];
  const float* W2  = (const float*)d_in[6];
  const float* as2 = (const float*)d_in[7];
  const float* ad2 = (const float*)d_in[8];
  const float* b2  = (const float*)d_in[9];
  const float* Wc1 = (const float*)d_in[10];
  const float* bc1 = (const float*)d_in[11];
  const float* Wc2 = (const float*)d_in[12];
  const float* bc2 = (const float*)d_in[13];
  float* out = (float*)d_out;

  char* p = (char*)d_ws; size_t off = 0;
  auto alloc = [&](size_t b){ void* r = p + off; off = (off + b + 255) & ~(size_t)255; return r; };
  unsigned short* xpad = (unsigned short*)alloc((size_t)NN*KP1*2);
  unsigned short* W1t  = (unsigned short*)alloc((size_t)512*KP1*2);
  unsigned short* W2t  = (unsigned short*)alloc((size_t)HID*F1*2);
  unsigned short* xp1  = (unsigned short*)alloc((size_t)NN*F1*2);
  unsigned short* h1   = (unsigned short*)alloc((size_t)NN*F1*2);
  float* xp2  = (float*)alloc((size_t)NN*HID*4);
  float* als1 = (float*)alloc((size_t)NN*NH*4);
  float* ald1 = (float*)alloc((size_t)NN*NH*4);
  float* als2 = (float*)alloc((size_t)NN*4);
  float* ald2 = (float*)alloc((size_t)NN*4);
  int* deg  = (int*)alloc((size_t)DEGPAD*4);
  int* cur  = (int*)alloc((size_t)NN*4);
  int* offs = (int*)alloc((size_t)(NN+1)*4);
  int* esrc = (int*)alloc((size_t)ET*4);

  hipMemsetAsync(deg, 0, (size_t)DEGPAD*4, stream);
  hipMemsetAsync(cur, 0, (size_t)NN*4, stream);

  k_pad_x<<<4096, 256, 0, stream>>>(x, xpad);
  k_prep<<<512, 256, 0, stream>>>(W1, W2, W1t, W2t);
  k_hist<<<(ET + 255)/256, 256, 0, stream>>>(ei, deg);
  k_scan<<<1, 1024, 0, stream>>>(deg, offs);
  k_scatter<<<(ET + 255)/256, 256, 0, stream>>>(ei, offs, cur, esrc);

  k_gemm<6, true, true, 8><<<dim3(782, 8), 256, 0, stream>>>(
      xpad, KP1, NN, W1t, (void*)xp1, F1, as1, ad1, als1, ald1);
  k_agg1<<<12500, 256, 0, stream>>>(offs, esrc, xp1, als1, ald1, b1, h1);

  k_gemm<16, false, true, 1><<<dim3(782, 1), 256, 0, stream>>>(
      h1, F1, NN, W2t, (void*)xp2, HID, as2, ad2, als2, ald2);
  k_agg2<<<12500, 256, 0, stream>>>(offs, esrc, xp2, als2, ald2, b2, Wc1, bc1, Wc2, bc2, out);
}

// Round 3
// 394.025 us; speedup vs baseline: 1.4840x; 1.0264x over previous
//
#include <hip/hip_runtime.h>

#define NN   50000
#define E0   800000
#define ET   850000
#define FIN  166
#define KP1  192
#define HID  64
#define NH   8
#define F1   512
#define SCHUNK 52
#define DEGPAD (1024*SCHUNK)

typedef __attribute__((ext_vector_type(8))) short short8;
typedef __attribute__((ext_vector_type(4))) float f32x4;
typedef __attribute__((ext_vector_type(4))) int int4v;
typedef unsigned short ush;

__device__ __forceinline__ float bf2f(unsigned short u){
  unsigned int x = ((unsigned int)u) << 16;
  return __builtin_bit_cast(float, x);
}
__device__ __forceinline__ unsigned short f2bf(float f){
  unsigned int x = __builtin_bit_cast(unsigned int, f);
  x += 0x7FFFu + ((x >> 16) & 1u);
  return (unsigned short)(x >> 16);
}

// ---- fused prep: pad/convert x, transpose+convert W1,W2, dst-degree histogram ----
__global__ __launch_bounds__(256) void k_prep_all(const float* __restrict__ x,
                                                  const float* __restrict__ W1,
                                                  const float* __restrict__ W2,
                                                  const int* __restrict__ ei,
                                                  ush* __restrict__ xpad,
                                                  ush* __restrict__ W1t,
                                                  ush* __restrict__ W2t,
                                                  int* __restrict__ deg){
  const int T0 = NN*KP1;
  const int T1 = T0 + 512*KP1;
  const int T2 = T1 + HID*F1;
  const int T3 = T2 + ET;
  int i = blockIdx.x*256 + threadIdx.x;
  if (i >= T3) return;
  if (i < T0){
    int n = i / KP1, k = i % KP1;
    xpad[i] = f2bf(k < FIN ? x[(size_t)n*FIN + k] : 0.f);
  } else if (i < T1){
    int j = i - T0; int col = j / KP1, k = j % KP1;
    W1t[j] = f2bf(k < FIN ? W1[(size_t)k*512 + col] : 0.f);
  } else if (i < T2){
    int j = i - T1; int col = j / F1, k = j % F1;
    W2t[j] = f2bf(W2[(size_t)k*HID + col]);
  } else {
    int e = i - T2;
    int dst = (e < E0) ? ei[E0 + e] : (e - E0);
    atomicAdd(&deg[dst], 1);
  }
}

// ---- exclusive scan of deg -> offs[NN+1], single block, int4 loads ----
__global__ __launch_bounds__(1024) void k_scan(const int* __restrict__ deg,
                                               int* __restrict__ offs){
  __shared__ int sums[1024];
  int t = threadIdx.x;
  int base = t * SCHUNK;
  int4v v[13];
  int loc = 0;
  #pragma unroll
  for (int c = 0; c < 13; c++){
    v[c] = *(const int4v*)(deg + base + c*4);
    loc += v[c].x + v[c].y + v[c].z + v[c].w;
  }
  sums[t] = loc; __syncthreads();
  for (int off = 1; off < 1024; off <<= 1){
    int s = (t >= off) ? sums[t - off] : 0;
    __syncthreads();
    sums[t] += s;
    __syncthreads();
  }
  int run = sums[t] - loc;
  #pragma unroll
  for (int c = 0; c < 13; c++){
    int i0 = base + c*4;
    if (i0 + 0 < NN) offs[i0 + 0] = run;  run += v[c].x;
    if (i0 + 1 < NN) offs[i0 + 1] = run;  run += v[c].y;
    if (i0 + 2 < NN) offs[i0 + 2] = run;  run += v[c].z;
    if (i0 + 3 < NN) offs[i0 + 3] = run;  run += v[c].w;
  }
  if (t == 1023) offs[NN] = sums[1023];
}

// ---- scatter edges into CSR-by-dst ----
__global__ __launch_bounds__(256) void k_scatter(const int* __restrict__ ei,
                                                 const int* __restrict__ offs,
                                                 int* __restrict__ cur,
                                                 int* __restrict__ esrc){
  for (int e = blockIdx.x*256 + threadIdx.x; e < ET; e += gridDim.x*256){
    int src, dst;
    if (e < E0){ src = ei[e]; dst = ei[E0 + e]; }
    else       { src = e - E0; dst = src; }
    int pos = offs[dst] + atomicAdd(&cur[dst], 1);
    esrc[pos] = src;
  }
}

// ---- GEMM1: xpad[NN,192] @ W1t^T -> xp1 bf16 [NN,512]; fused per-head logits ----
// 128x128 tile, 4 waves 2x2, wave=64x64 (4x4 16x16x32 frags). Wave col-span = one head.
__global__ __launch_bounds__(256) void k_gemm1(const ush* __restrict__ xpad,
                                               const ush* __restrict__ W1t,
                                               const float* __restrict__ a_s,
                                               const float* __restrict__ a_d,
                                               ush* __restrict__ xp1,
                                               float* __restrict__ als,
                                               float* __restrict__ ald){
  __shared__ ush As[128][40];
  __shared__ ush Bs[128][40];
  const int m0 = blockIdx.x*128, n0 = blockIdx.y*128;
  const int t = threadIdx.x, wid = t>>6, l = t&63;
  const int wr = wid>>1, wc = wid&1;
  const int lr = l&15, ksl = (l>>4)*8;
  const int srow = t>>1, sc = (t&1)*16;

  f32x4 acc[4][4];
  #pragma unroll
  for (int m = 0; m < 4; m++)
    #pragma unroll
    for (int n = 0; n < 4; n++)
      #pragma unroll
      for (int j = 0; j < 4; j++) acc[m][n][j] = 0.f;

  const int gr = m0 + srow;
  const ush* Ap = xpad + (size_t)gr*KP1 + sc;
  const ush* Bp = W1t + (size_t)(n0 + srow)*KP1 + sc;

  for (int s = 0; s < 6; s++){
    const int kk = s*32;
    short8 a0, a1;
    #pragma unroll
    for (int j = 0; j < 8; j++){ a0[j] = 0; a1[j] = 0; }
    if (gr < NN){ a0 = *(const short8*)(Ap + kk); a1 = *(const short8*)(Ap + kk + 8); }
    short8 b0 = *(const short8*)(Bp + kk);
    short8 b1 = *(const short8*)(Bp + kk + 8);
    *(short8*)&As[srow][sc]   = a0;
    *(short8*)&As[srow][sc+8] = a1;
    *(short8*)&Bs[srow][sc]   = b0;
    *(short8*)&Bs[srow][sc+8] = b1;
    __syncthreads();
    short8 af[4], bfr[4];
    #pragma unroll
    for (int m = 0; m < 4; m++) af[m]  = *(const short8*)&As[wr*64 + m*16 + lr][ksl];
    #pragma unroll
    for (int n = 0; n < 4; n++) bfr[n] = *(const short8*)&Bs[wc*64 + n*16 + lr][ksl];
    #pragma unroll
    for (int m = 0; m < 4; m++)
      #pragma unroll
      for (int n = 0; n < 4; n++)
        acc[m][n] = __builtin_amdgcn_mfma_f32_16x16x32_bf16(af[m], bfr[n], acc[m][n], 0, 0, 0);
    __syncthreads();
  }

  #pragma unroll
  for (int m = 0; m < 4; m++)
    #pragma unroll
    for (int n = 0; n < 4; n++)
      #pragma unroll
      for (int j = 0; j < 4; j++){
        int row = m0 + wr*64 + m*16 + (l>>4)*4 + j;
        int col = n0 + wc*64 + n*16 + lr;
        if (row < NN) xp1[(size_t)row*F1 + col] = f2bf(acc[m][n][j]);
      }

  const int head = blockIdx.y*2 + wc;
  float asv[4], adv[4];
  #pragma unroll
  for (int n = 0; n < 4; n++){
    asv[n] = a_s[head*64 + n*16 + lr];
    adv[n] = a_d[head*64 + n*16 + lr];
  }
  #pragma unroll
  for (int m = 0; m < 4; m++)
    #pragma unroll
    for (int j = 0; j < 4; j++){
      float ps = 0.f, pd = 0.f;
      #pragma unroll
      for (int n = 0; n < 4; n++){
        ps = fmaf(acc[m][n][j], asv[n], ps);
        pd = fmaf(acc[m][n][j], adv[n], pd);
      }
      #pragma unroll
      for (int o = 1; o < 16; o <<= 1){
        ps += __shfl_xor(ps, o, 64);
        pd += __shfl_xor(pd, o, 64);
      }
      if (lr == 0){
        int row = m0 + wr*64 + m*16 + (l>>4)*4 + j;
        if (row < NN){
          als[(size_t)row*NH + head] = fminf(fmaxf(ps, -30.f), 30.f);
          ald[(size_t)row*NH + head] = fminf(fmaxf(pd, -30.f), 30.f);
        }
      }
    }
}

// ---- GEMM2: h1[NN,512] @ W2t^T -> xp2 bf16 [NN,64]; fused logits (1 head) ----
// 128x64 tile, 4 waves stacked in M (wave=32x64: 2x4 frags).
__global__ __launch_bounds__(256) void k_gemm2(const ush* __restrict__ h1,
                                               const ush* __restrict__ W2t,
                                               const float* __restrict__ a_s,
                                               const float* __restrict__ a_d,
                                               ush* __restrict__ xp2,
                                               float* __restrict__ als,
                                               float* __restrict__ ald){
  __shared__ ush As[128][40];
  __shared__ ush Bs[64][40];
  const int m0 = blockIdx.x*128;
  const int t = threadIdx.x, wid = t>>6, l = t&63;
  const int lr = l&15, ksl = (l>>4)*8;
  const int srow = t>>1, sc = (t&1)*16;

  f32x4 acc[2][4];
  #pragma unroll
  for (int m = 0; m < 2; m++)
    #pragma unroll
    for (int n = 0; n < 4; n++)
      #pragma unroll
      for (int j = 0; j < 4; j++) acc[m][n][j] = 0.f;

  const int gr = m0 + srow;
  const ush* Ap = h1 + (size_t)gr*F1 + sc;
  const ush* Bp = W2t + (size_t)srow*F1 + sc;   // only t<128 uses (rows 0..63)

  for (int s = 0; s < 16; s++){
    const int kk = s*32;
    short8 a0, a1;
    #pragma unroll
    for (int j = 0; j < 8; j++){ a0[j] = 0; a1[j] = 0; }
    if (gr < NN){ a0 = *(const short8*)(Ap + kk); a1 = *(const short8*)(Ap + kk + 8); }
    *(short8*)&As[srow][sc]   = a0;
    *(short8*)&As[srow][sc+8] = a1;
    if (t < 128){
      short8 b0 = *(const short8*)(Bp + kk);
      short8 b1 = *(const short8*)(Bp + kk + 8);
      *(short8*)&Bs[srow][sc]   = b0;
      *(short8*)&Bs[srow][sc+8] = b1;
    }
    __syncthreads();
    short8 af[2], bfr[4];
    #pragma unroll
    for (int m = 0; m < 2; m++) af[m]  = *(const short8*)&As[wid*32 + m*16 + lr][ksl];
    #pragma unroll
    for (int n = 0; n < 4; n++) bfr[n] = *(const short8*)&Bs[n*16 + lr][ksl];
    #pragma unroll
    for (int m = 0; m < 2; m++)
      #pragma unroll
      for (int n = 0; n < 4; n++)
        acc[m][n] = __builtin_amdgcn_mfma_f32_16x16x32_bf16(af[m], bfr[n], acc[m][n], 0, 0, 0);
    __syncthreads();
  }

  #pragma unroll
  for (int m = 0; m < 2; m++)
    #pragma unroll
    for (int n = 0; n < 4; n++)
      #pragma unroll
      for (int j = 0; j < 4; j++){
        int row = m0 + wid*32 + m*16 + (l>>4)*4 + j;
        int col = n*16 + lr;
        if (row < NN) xp2[(size_t)row*HID + col] = f2bf(acc[m][n][j]);
      }

  float asv[4], adv[4];
  #pragma unroll
  for (int n = 0; n < 4; n++){
    asv[n] = a_s[n*16 + lr];
    adv[n] = a_d[n*16 + lr];
  }
  #pragma unroll
  for (int m = 0; m < 2; m++)
    #pragma unroll
    for (int j = 0; j < 4; j++){
      float ps = 0.f, pd = 0.f;
      #pragma unroll
      for (int n = 0; n < 4; n++){
        ps = fmaf(acc[m][n][j], asv[n], ps);
        pd = fmaf(acc[m][n][j], adv[n], pd);
      }
      #pragma unroll
      for (int o = 1; o < 16; o <<= 1){
        ps += __shfl_xor(ps, o, 64);
        pd += __shfl_xor(pd, o, 64);
      }
      if (lr == 0){
        int row = m0 + wid*32 + m*16 + (l>>4)*4 + j;
        if (row < NN){
          als[row] = fminf(fmaxf(ps, -30.f), 30.f);
          ald[row] = fminf(fmaxf(pd, -30.f), 30.f);
        }
      }
    }
}

// ---- layer-1 aggregation: wave per dst; chunked esrc via shfl; 4-way unroll ----
__global__ __launch_bounds__(256) void k_agg1(const int* __restrict__ offs,
                                              const int* __restrict__ esrc,
                                              const ush* __restrict__ xp1,
                                              const float* __restrict__ als,
                                              const float* __restrict__ ald,
                                              const float* __restrict__ b1,
                                              ush* __restrict__ h1){
  int w = (blockIdx.x*256 + threadIdx.x) >> 6;
  int l = threadIdx.x & 63;
  if (w >= NN) return;
  int h = l >> 3;
  int f0 = l * 8;
  float ad = ald[w*NH + h];
  int s0 = offs[w], s1 = offs[w+1];
  float accA[8], accB[8];
  #pragma unroll
  for (int j = 0; j < 8; j++){ accA[j] = 0.f; accB[j] = 0.f; }
  float den = 0.f;

  for (int base = s0; base < s1; base += 64){
    int cnt = min(64, s1 - base);
    int myE = (base + l < s1) ? esrc[base + l] : 0;
    int j = 0;
    for (; j + 4 <= cnt; j += 4){
      int sA = __shfl(myE, j,   64);
      int sB = __shfl(myE, j+1, 64);
      int sC = __shfl(myE, j+2, 64);
      int sD = __shfl(myE, j+3, 64);
      float eA = als[sA*NH + h] + ad;
      float eB = als[sB*NH + h] + ad;
      float eC = als[sC*NH + h] + ad;
      float eD = als[sD*NH + h] + ad;
      eA = fmaxf(eA, 0.2f*eA); eB = fmaxf(eB, 0.2f*eB);
      eC = fmaxf(eC, 0.2f*eC); eD = fmaxf(eD, 0.2f*eD);
      float wA = __expf(eA), wB = __expf(eB), wC = __expf(eC), wD = __expf(eD);
      short8 vA = *(const short8*)(xp1 + (size_t)sA*F1 + f0);
      short8 vB = *(const short8*)(xp1 + (size_t)sB*F1 + f0);
      short8 vC = *(const short8*)(xp1 + (size_t)sC*F1 + f0);
      short8 vD = *(const short8*)(xp1 + (size_t)sD*F1 + f0);
      den += (wA + wB) + (wC + wD);
      #pragma unroll
      for (int jj = 0; jj < 8; jj++){
        accA[jj] = fmaf(wA, bf2f((ush)vA[jj]), accA[jj]);
        accB[jj] = fmaf(wB, bf2f((ush)vB[jj]), accB[jj]);
        accA[jj] = fmaf(wC, bf2f((ush)vC[jj]), accA[jj]);
        accB[jj] = fmaf(wD, bf2f((ush)vD[jj]), accB[jj]);
      }
    }
    for (; j < cnt; j++){
      int sA = __shfl(myE, j, 64);
      float eA = als[sA*NH + h] + ad;
      eA = fmaxf(eA, 0.2f*eA);
      float wA = __expf(eA);
      short8 vA = *(const short8*)(xp1 + (size_t)sA*F1 + f0);
      den += wA;
      #pragma unroll
      for (int jj = 0; jj < 8; jj++)
        accA[jj] = fmaf(wA, bf2f((ush)vA[jj]), accA[jj]);
    }
  }
  float inv = 1.f / den;
  #pragma unroll
  for (int jj = 0; jj < 8; jj++){
    float o = (accA[jj] + accB[jj])*inv + b1[f0 + jj];
    o = o > 0.f ? o : expm1f(o);
    h1[(size_t)w*F1 + f0 + jj] = f2bf(o);
  }
}

// ---- layer-2 aggregation (bf16 gather) + fused classifier ----
__global__ __launch_bounds__(256) void k_agg2(const int* __restrict__ offs,
                                              const int* __restrict__ esrc,
                                              const ush* __restrict__ xp2,
                                              const float* __restrict__ als,
                                              const float* __restrict__ ald,
                                              const float* __restrict__ b2,
                                              const float* __restrict__ Wc1,
                                              const float* __restrict__ bc1,
                                              const float* __restrict__ Wc2,
                                              const float* __restrict__ bc2,
                                              float* __restrict__ out){
  int w = (blockIdx.x*256 + threadIdx.x) >> 6;
  int l = threadIdx.x & 63;
  if (w >= NN) return;
  float ad = ald[w];
  int s0 = offs[w], s1 = offs[w+1];
  float accA = 0.f, accB = 0.f, den = 0.f;

  for (int base = s0; base < s1; base += 64){
    int cnt = min(64, s1 - base);
    int myE = (base + l < s1) ? esrc[base + l] : 0;
    int j = 0;
    for (; j + 4 <= cnt; j += 4){
      int sA = __shfl(myE, j,   64);
      int sB = __shfl(myE, j+1, 64);
      int sC = __shfl(myE, j+2, 64);
      int sD = __shfl(myE, j+3, 64);
      float eA = als[sA] + ad, eB = als[sB] + ad, eC = als[sC] + ad, eD = als[sD] + ad;
      eA = fmaxf(eA, 0.2f*eA); eB = fmaxf(eB, 0.2f*eB);
      eC = fmaxf(eC, 0.2f*eC); eD = fmaxf(eD, 0.2f*eD);
      float wA = __expf(eA), wB = __expf(eB), wC = __expf(eC), wD = __expf(eD);
      float xA = bf2f(xp2[(size_t)sA*HID + l]);
      float xB = bf2f(xp2[(size_t)sB*HID + l]);
      float xC = bf2f(xp2[(size_t)sC*HID + l]);
      float xD = bf2f(xp2[(size_t)sD*HID + l]);
      den += (wA + wB) + (wC + wD);
      accA = fmaf(wA, xA, accA); accB = fmaf(wB, xB, accB);
      accA = fmaf(wC, xC, accA); accB = fmaf(wD, xD, accB);
    }
    for (; j < cnt; j++){
      int sA = __shfl(myE, j, 64);
      float eA = als[sA] + ad;
      eA = fmaxf(eA, 0.2f*eA);
      float wA = __expf(eA);
      den += wA;
      accA = fmaf(wA, bf2f(xp2[(size_t)sA*HID + l]), accA);
    }
  }
  float h2 = (accA + accB) / den + b2[l];
  float r = 0.f;
  #pragma unroll
  for (int k = 0; k < 64; k++){
    float hk = __shfl(h2, k, 64);
    r = fmaf(hk, Wc1[k*HID + l], r);
  }
  r += bc1[l];
  r = fmaxf(r, 0.f);
  float p0 = r * Wc2[l*2 + 0];
  float p1 = r * Wc2[l*2 + 1];
  #pragma unroll
  for (int o = 1; o < 64; o <<= 1){
    p0 += __shfl_xor(p0, o, 64);
    p1 += __shfl_xor(p1, o, 64);
  }
  if (l == 0){
    out[(size_t)w*2 + 0] = p0 + bc2[0];
    out[(size_t)w*2 + 1] = p1 + bc2[1];
  }
}

extern "C" void kernel_launch(void* const* d_in, const int* in_sizes, int n_in,
                              void* d_out, int out_size, void* d_ws, size_t ws_size,
                              hipStream_t stream){
  const float* x   = (const float*)d_in[0];
  const int*   ei  = (const int*)  d_in[1];
  const float* W1  = (const float*)d_in[2];
  const float* as1 = (const float*)d_in[3];
  const float* ad1 = (const float*)d_in[4];
  const float* b1  = (const float*)d_in[5];
  const float* W2  = (const float*)d_in[6];
  const float* as2 = (const float*)d_in[7];
  const float* ad2 = (const float*)d_in[8];
  const float* b2  = (const float*)d_in[9];
  const float* Wc1 = (const float*)d_in[10];
  const float* bc1 = (const float*)d_in[11];
  const float* Wc2 = (const float*)d_in[12];
  const float* bc2 = (const float*)d_in[13];
  float* out = (float*)d_out;

  char* p = (char*)d_ws; size_t off = 0;
  auto alloc = [&](size_t b){ void* r = p + off; off = (off + b + 255) & ~(size_t)255; return r; };
  ush* xpad = (ush*)alloc((size_t)NN*KP1*2);
  ush* W1t  = (ush*)alloc((size_t)512*KP1*2);
  ush* W2t  = (ush*)alloc((size_t)HID*F1*2);
  ush* xp1  = (ush*)alloc((size_t)NN*F1*2);
  ush* h1   = (ush*)alloc((size_t)NN*F1*2);
  ush* xp2  = (ush*)alloc((size_t)NN*HID*2);
  float* als1 = (float*)alloc((size_t)NN*NH*4);
  float* ald1 = (float*)alloc((size_t)NN*NH*4);
  float* als2 = (float*)alloc((size_t)NN*4);
  float* ald2 = (float*)alloc((size_t)NN*4);
  int* deg  = (int*)alloc((size_t)DEGPAD*4);
  int* cur  = (int*)alloc((size_t)NN*4);
  int* offs = (int*)alloc((size_t)(NN+1)*4);
  int* esrc = (int*)alloc((size_t)ET*4);

  hipMemsetAsync(deg, 0, (size_t)DEGPAD*4, stream);
  hipMemsetAsync(cur, 0, (size_t)NN*4, stream);

  const int T3 = NN*KP1 + 512*KP1 + HID*F1 + ET;
  k_prep_all<<<(T3 + 255)/256, 256, 0, stream>>>(x, W1, W2, ei, xpad, W1t, W2t, deg);
  k_scan<<<1, 1024, 0, stream>>>(deg, offs);
  k_scatter<<<(ET + 255)/256, 256, 0, stream>>>(ei, offs, cur, esrc);

  k_gemm1<<<dim3(391, 4), 256, 0, stream>>>(xpad, W1t, as1, ad1, xp1, als1, ald1);
  k_agg1<<<12500, 256, 0, stream>>>(offs, esrc, xp1, als1, ald1, b1, h1);

  k_gemm2<<<391, 256, 0, stream>>>(h1, W2t, as2, ad2, xp2, als2, ald2);
  k_agg2<<<12500, 256, 0, stream>>>(offs, esrc, xp2, als2, ald2, b2, Wc1, bc1, Wc2, bc2, out);
}